// Round 9
// baseline (350.422 us; speedup 1.0000x reference)
//
#include <hip/hip_runtime.h>
#include <hip/hip_bf16.h>
#include <stdint.h>

// Problem: B=16, S=2048, I=1024, H=1024  (all fp32 in/out)
// out[b,s,h] = tanh( sum_i x[b,s,i]*W_ih[h,i] + b_ih[h] + sum_k hx[b,k]*W_hh[h,k] + b_hh[h] )
// M = B*S = 32768, N = H = 1024, K = I = 1024.
//
// v8 (resubmit after infra failure; audit found no defect): eliminate the
// standalone X fp32->bf16 pass (~60 us wall, R0/R5-R7 vs R1-R3 ledger) by
// GLDS-staging A as RAW FP32 into LDS and converting at fragment-read time
// (2x ds_read_b128 + 4x v_cvt_pk_bf16_f32 per fragment). Keeps the proven
// zero-VALU wave-uniform GLDS staging path; X traffic 268 -> 134 MB.
// A-fp32 stored as two 8 KB kh-planes, each with the PROVEN 64B-row/4-slot
// XOR swizzle geometry (conflict-free per the per-8-lane phase model that
// matches the measured-0 bf16 layout). GEMM structure = R6's (double-buffer
// 48 KB, stage-at-start, one __syncthreads/iter), XCD-corrected mapping.
// prep reverts to R1's hterm + W-convert only (measured other = 162 us).

#define M_TOT 32768
#define N_TOT 1024
#define K_TOT 1024

typedef short short8 __attribute__((ext_vector_type(8)));   // 8 bf16 (4 VGPRs)
typedef float f32x4  __attribute__((ext_vector_type(4)));   // 4 fp32

// ---- workspace layout (bytes) ----
#define WS_WBF_OFF 0          // W_bf: 1048576 bf16 = 2 MB
#define WS_HT_OFF  2097152    // h_term: 16384 fp32

__device__ __forceinline__ unsigned short f32_to_bf16_rne(float f) {
    union { float f; unsigned int u; } v; v.f = f;
    unsigned int u = v.u;
    unsigned int r = u + 0x7fffu + ((u >> 16) & 1u);
    return (unsigned short)(r >> 16);
}

// packed RNE f32->bf16 (same numerics as R1-R3, which passed with identical absmax)
__device__ __forceinline__ unsigned int cvt_pk_bf16(float lo, float hi) {
    unsigned int r;
    asm("v_cvt_pk_bf16_f32 %0, %1, %2" : "=v"(r) : "v"(lo), "v"(hi));
    return r;
}

__device__ __forceinline__ float fast_tanh(float z) {
    // tanh(z) = 1 - 2/(exp(2z)+1); __expf -> v_exp_f32. Saturates at +-inf.
    float e = __expf(2.0f * z);
    return 1.0f - 2.0f / (e + 1.0f);
}

// ---------------- kernel 1: prep = h_term + W_ih fp32->bf16 (R1 structure) ----------------
// blocks [0,4096): h_term[b,h] = hx[b,:].W_hh[h,:] + b_ih[h] + b_hh[h]  (1 wave each, 4/block)
// blocks [4096,4224): convert W_ih (131072 vec8 groups over 32768 threads, 4 iters)
__global__ void prep_kernel(const float* __restrict__ hx,
                            const float* __restrict__ whh,
                            const float* __restrict__ bih,
                            const float* __restrict__ bhh,
                            const float* __restrict__ wih,
                            float* __restrict__ ht,
                            unsigned short* __restrict__ wbf) {
    if (blockIdx.x < 4096) {
        int lane = threadIdx.x & 63;
        int w    = threadIdx.x >> 6;
        int wg   = blockIdx.x * 4 + w;        // 0..16383
        int b = wg >> 10, h = wg & 1023;
        const float* hr = hx  + (long long)b * 1024;
        const float* wr = whh + (long long)h * 1024;
        float s = 0.f;
#pragma unroll
        for (int p = 0; p < 4; ++p) {
            int idx = p * 256 + lane * 4;
            float4 a = *(const float4*)(hr + idx);
            float4 c = *(const float4*)(wr + idx);
            s += a.x * c.x + a.y * c.y + a.z * c.z + a.w * c.w;
        }
#pragma unroll
        for (int d = 32; d > 0; d >>= 1) s += __shfl_down(s, d, 64);
        if (lane == 0) ht[wg] = s + bih[h] + bhh[h];
    } else {
        int g = (blockIdx.x - 4096) * 256 + threadIdx.x;   // 0..32767
        for (int v = g; v < 131072; v += 32768) {
            long long base = (long long)v * 8;
            float4 a = *(const float4*)(wih + base);
            float4 b = *(const float4*)(wih + base + 4);
            union { unsigned short s[8]; uint4 u; } o;
            o.s[0] = f32_to_bf16_rne(a.x); o.s[1] = f32_to_bf16_rne(a.y);
            o.s[2] = f32_to_bf16_rne(a.z); o.s[3] = f32_to_bf16_rne(a.w);
            o.s[4] = f32_to_bf16_rne(b.x); o.s[5] = f32_to_bf16_rne(b.y);
            o.s[6] = f32_to_bf16_rne(b.z); o.s[7] = f32_to_bf16_rne(b.w);
            *(uint4*)(wbf + base) = o.u;
        }
    }
}

// ---------------- kernel 2: fp32-A GEMM + tanh epilogue ----------------
// 128x128 tile, BK=32, 256 threads = 4 waves in 2x2, each wave 64x64 (4x4 MFMA
// 16x16x32). LDS: TWO buffers of 24 KB; buffer p at [p*24576):
//   A-fp32 [0,16384): two 8 KB planes, plane kh holds floats [r][16kh..16kh+15];
//     each plane = 128 rows x 64 B, slot c of row r stored at ((c+(r>>1))&3)
//     -- IDENTICAL geometry to the proven 0-conflict bf16 layout.
//   B-bf16 [16384,24576): unchanged proven layout (rows 64 B, 4-slot swizzle).
// Staging: GLDS width=16 with the inverse swizzle pre-applied to the per-lane
// GLOBAL address (LDS dest linear). A = 4 instr/thread, B = 2 instr/thread.
// Fragment read: A needs floats [rr][8q..8q+7] = plane q>>1, chunks
// {2(q&1), 2(q&1)+1} -> 2x ds_read_b128 -> 4x cvt_pk -> short8 af.
#define GLDS16(gp, lp) \
    __builtin_amdgcn_global_load_lds((const __attribute__((address_space(1))) void*)(gp), \
                                     (__attribute__((address_space(3))) void*)(lp), 16, 0, 0)

// One K-iteration: STAGE tile (KNEXT/32) into buf[P^1] FIRST (k+1 prefetch),
// then ds_read + cvt + 16 MFMA from buf[P], then one barrier (vmcnt(0) drain
// covered by the compute phase, R6-verified structure).
#define KITER(KNEXT, P, STAGE)                                                 \
  {                                                                            \
    if (STAGE) {                                                               \
      _Pragma("unroll")                                                        \
      for (int j = 0; j < 4; ++j)                                              \
        GLDS16(gA[j] + (KNEXT), lA[j] + ((P) ^ 1) * 24576);                    \
      GLDS16(gB0 + (KNEXT), lB0 + ((P) ^ 1) * 24576);                          \
      GLDS16(gB1 + (KNEXT), lB1 + ((P) ^ 1) * 24576);                          \
    }                                                                          \
    {                                                                          \
      const char* lb = lds + (P) * 24576;                                      \
      f32x4 alo[4], ahi[4]; short8 bfr[4];                                     \
      _Pragma("unroll")                                                        \
      for (int t4 = 0; t4 < 4; ++t4) {                                         \
        alo[t4] = *(const f32x4*)(lb + offA0[t4]);                             \
        ahi[t4] = *(const f32x4*)(lb + offA1[t4]);                             \
        bfr[t4] = *(const short8*)(lb + offB[t4]);                             \
      }                                                                        \
      short8 af[4];                                                            \
      _Pragma("unroll")                                                        \
      for (int t4 = 0; t4 < 4; ++t4) {                                         \
        union { uint4 u; short8 s; } cv;                                       \
        cv.u.x = cvt_pk_bf16(alo[t4].x, alo[t4].y);                            \
        cv.u.y = cvt_pk_bf16(alo[t4].z, alo[t4].w);                            \
        cv.u.z = cvt_pk_bf16(ahi[t4].x, ahi[t4].y);                            \
        cv.u.w = cvt_pk_bf16(ahi[t4].z, ahi[t4].w);                            \
        af[t4] = cv.s;                                                         \
      }                                                                        \
      _Pragma("unroll")                                                        \
      for (int mt = 0; mt < 4; ++mt)                                           \
        _Pragma("unroll")                                                      \
        for (int nt = 0; nt < 4; ++nt)                                         \
          acc[mt][nt] = __builtin_amdgcn_mfma_f32_16x16x32_bf16(               \
              af[mt], bfr[nt], acc[mt][nt], 0, 0, 0);                          \
    }                                                                          \
    __syncthreads();                                                           \
  }

__global__ __launch_bounds__(256, 3) void gemm_tanh_kernel(
    const float* __restrict__ X,            // [32768,1024] fp32 (read DIRECTLY)
    const unsigned short* __restrict__ Bm,  // [1024,1024]  bf16 (W_ih, row n K-contig)
    const float* __restrict__ ht,           // [16,1024]
    float* __restrict__ out)                // [32768,1024] fp32
{
    __shared__ __align__(16) char lds[49152];

    const int tid = threadIdx.x;
    const int w = tid >> 6, l = tid & 63;

    // XCD-corrected mapping (verified: kills the 4x A over-fetch). bid
    // round-robins over 8 XCDs; XCD x gets contiguous widx chunk, n innermost.
    const int bid  = blockIdx.x;
    const int widx = (bid & 7) * 256 + (bid >> 3);
    const int tile_m = widx >> 3;      // 0..255
    const int tile_n = widx & 7;       // 0..7
    const int m0 = tile_m << 7, n0 = tile_n << 7;

    // ---- A staging (fp32, 4 GLDS/thread) ----
    // instr j covers row64s R in [(w*4+j)*16, +16); lane l -> R += l>>2,
    // slot l&3. R -> plane kh = R>>7, tile row r = R&127. Slot s holds global
    // float chunk qg = (s - (r>>1)) & 3 (inverse of the read swizzle).
    const float* gA[4];
    char* lA[4];
#pragma unroll
    for (int j = 0; j < 4; ++j) {
        int R  = (w * 4 + j) * 16 + (l >> 2);
        int kh = R >> 7, r = R & 127;
        int qg = ((l & 3) - (r >> 1)) & 3;
        gA[j] = X + (long long)(m0 + r) * K_TOT + kh * 16 + qg * 4;
        lA[j] = lds + (w * 4 + j) * 1024;      // wave-uniform; HW adds lane*16
    }

    // ---- B staging (bf16, 2 GLDS/thread, proven) ----
    const int r0 = (w * 2 + 0) * 16 + (l >> 2);
    const int r1 = (w * 2 + 1) * 16 + (l >> 2);
    const int slot = l & 3;
    const int qg0 = (slot - (r0 >> 1)) & 3;
    const int qg1 = (slot - (r1 >> 1)) & 3;
    const unsigned short* gB0 = Bm + (long long)(n0 + r0) * K_TOT + qg0 * 8;
    const unsigned short* gB1 = Bm + (long long)(n0 + r1) * K_TOT + qg1 * 8;
    char* lB0 = lds + 16384 + (w * 2 + 0) * 1024;
    char* lB1 = lds + 16384 + (w * 2 + 1) * 1024;

    // ---- fragment read offsets (within one 24 KB buffer) ----
    const int wm = w & 1, wn = w >> 1;       // 2x2 wave grid
    const int lm = l & 15, q = l >> 4;       // MFMA operand: row = lm, k-chunk = q
    int offA0[4], offA1[4], offB[4];
#pragma unroll
    for (int t = 0; t < 4; ++t) {
        int rr = wm * 64 + t * 16 + lm;
        int abase = (q >> 1) * 8192 + rr * 64;   // plane kh = q>>1
        int c0 = 2 * (q & 1);                    // chunks {c0, c0+1} = floats 8q..8q+7
        offA0[t] = abase + (((c0 + 0 + (rr >> 1)) & 3) << 4);
        offA1[t] = abase + (((c0 + 1 + (rr >> 1)) & 3) << 4);
        int nn = wn * 64 + t * 16 + lm;
        offB[t] = 16384 + nn * 64 + (((q + (nn >> 1)) & 3) << 4);
    }

    f32x4 acc[4][4];
#pragma unroll
    for (int i = 0; i < 4; ++i)
#pragma unroll
        for (int j = 0; j < 4; ++j)
            acc[i][j] = (f32x4){0.f, 0.f, 0.f, 0.f};

    // ---- prologue: stage tile 0 into buf0 ----
#pragma unroll
    for (int j = 0; j < 4; ++j) GLDS16(gA[j], lA[j]);
    GLDS16(gB0, lB0);
    GLDS16(gB1, lB1);
    __syncthreads();

    // ---- main loop: 32 K-iters; iter i computes buf(i&1), stages buf(i&1)^1 ----
    for (int i = 0; i < 30; i += 2) {
        KITER((i + 1) * 32, 0, true);
        KITER((i + 2) * 32, 1, true);
    }
    KITER(31 * 32, 0, true);    // iter 30: compute buf0, stage k=31 -> buf1
    KITER(0,       1, false);   // iter 31: compute buf1, no stage

    // ---- epilogue: out = tanh(acc + h_term[b, n]) ----
    // C/D layout: col = lane&15 (n), row = (lane>>4)*4 + reg (m). [m89-verified]
    const int b = tile_m >> 4;   // 16 m-tiles per batch element
    float htv[4];
#pragma unroll
    for (int nt = 0; nt < 4; ++nt)
        htv[nt] = ht[b * 1024 + n0 + wn * 64 + nt * 16 + lm];

#pragma unroll
    for (int mt = 0; mt < 4; ++mt) {
#pragma unroll
        for (int nt = 0; nt < 4; ++nt) {
            int n = n0 + wn * 64 + nt * 16 + lm;
#pragma unroll
            for (int r = 0; r < 4; ++r) {
                int m = m0 + wm * 64 + mt * 16 + q * 4 + r;
                float z = acc[mt][nt][r] + htv[nt];
                out[(long long)m * N_TOT + n] = fast_tanh(z);
            }
        }
    }
}

extern "C" void kernel_launch(void* const* d_in, const int* in_sizes, int n_in,
                              void* d_out, int out_size, void* d_ws, size_t ws_size,
                              hipStream_t stream) {
    const float* x    = (const float*)d_in[0];   // [16,2048,1024]
    const float* hx   = (const float*)d_in[1];   // [16,1024]
    const float* wih  = (const float*)d_in[2];   // [1024,1024]
    const float* whh  = (const float*)d_in[3];   // [1024,1024]
    const float* bih  = (const float*)d_in[4];   // [1024]
    const float* bhh  = (const float*)d_in[5];   // [1024]
    float* out = (float*)d_out;

    unsigned short* wbf = (unsigned short*)((char*)d_ws + WS_WBF_OFF);
    float*          htp = (float*)((char*)d_ws + WS_HT_OFF);

    // prep: h_term (blocks 0..4095) + W convert (blocks 4096..4223)
    prep_kernel<<<4224, 256, 0, stream>>>(hx, whh, bih, bhh, wih, htp, wbf);
    // GEMM + tanh: reads X fp32 directly; 256 m-tiles x 8 n-tiles, XCD-remapped
    gemm_tanh_kernel<<<2048, 256, 0, stream>>>(x, wbf, htp, out);
}